// Round 2
// baseline (566.066 us; speedup 1.0000x reference)
//
#include <hip/hip_runtime.h>
#include <hip/hip_bf16.h>
#include <stdint.h>

#define NN 4096
#define MAXNZ 1536   // cap on nnz per row of a2 (expected ~270, max ~<800)

// ---------------------------------------------------------------------------
// K1: build sorted neighbor lists (ascending col index) + true degree.
// One wave per row; ballot-compaction preserves index order.
// ---------------------------------------------------------------------------
__global__ __launch_bounds__(256) void nbr_k(const float* __restrict__ adj,
                                             int* __restrict__ nbr,
                                             int* __restrict__ deg) {
    int tid = threadIdx.x;
    int wv = tid >> 6, ln = tid & 63;
    int v = blockIdx.x * 4 + wv;
    size_t rb = (size_t)v * NN;
    int total = 0;
    for (int base = 0; base < NN; base += 64) {
        float val = adj[rb + base + ln];
        bool p = val > 0.5f;
        unsigned long long m = __ballot(p);
        if (p) {
            int pos = total + __popcll(m & ((1ull << ln) - 1ull));
            if (pos < 64) nbr[v * 64 + pos] = base + ln;
        }
        total += __popcll(m);
    }
    if (ln == 0) deg[v] = total;
}

// ---------------------------------------------------------------------------
// K2: cr_feat (cols 0..3) + degree_feat (cols 12..14). One wave per node.
// Closed neighborhood = sorted {v} ∪ N(v)  (matches jax top_k stable order).
// 64-bit bitmask per member row; E/W via common-neighbor popcounts,
// T = trace(S^3)/6.
// ---------------------------------------------------------------------------
__global__ __launch_bounds__(256) void crfeat_k(const float* __restrict__ adj,
                                                const int* __restrict__ nbr,
                                                const int* __restrict__ deg,
                                                float* __restrict__ feats) {
    __shared__ unsigned long long rows[4][64];
    __shared__ int mems[4][64];
    int tid = threadIdx.x;
    int wv = tid >> 6, ln = tid & 63;
    int v = blockIdx.x * 4 + wv;

    int dv = deg[v];
    int degL = min(dv, 64);
    int c = min(dv + 1, 64);

    // position of v within sorted member list = #neighbors with index < v
    int isless = (ln < degL && nbr[v * 64 + ln] < v) ? 1 : 0;
    int pos = isless;
    #pragma unroll
    for (int off = 32; off; off >>= 1) pos += __shfl_xor(pos, off, 64);

    int mem = 0;
    if (ln < c) {
        if (ln < pos)       mem = nbr[v * 64 + ln];
        else if (ln == pos) mem = v;
        else                mem = nbr[v * 64 + ln - 1];
    }
    mems[wv][ln] = mem;
    __syncthreads();

    unsigned long long mask = 0;
    if (ln < c) {
        if (ln == pos) {
            mask = (c >= 64 ? ~0ull : ((1ull << c) - 1ull)) ^ (1ull << pos);
        } else {
            size_t rowbase = (size_t)mem * NN;
            for (int j = 0; j < c; j++) {
                if (j == ln) continue;
                int mj = mems[wv][j];
                if (adj[rowbase + mj] > 0.5f) mask |= 1ull << j;
            }
        }
    }
    rows[wv][ln] = mask;
    __syncthreads();

    int tpart = 0;
    float epart = 0.f, wpart = 0.f;
    if (ln < c) {
        unsigned long long mm = mask;
        while (mm) {
            int j = __ffsll(mm) - 1;
            mm &= mm - 1;
            tpart += __popcll(mask & rows[wv][j]);
        }
        if (ln != pos) {
            int cn = __popcll(rows[wv][pos] & mask);
            float D = (float)cn + 1.0f;
            epart = D;
            wpart = D * (D - 1.0f) * 0.5f;
        }
    }
    float es = epart, wsum = wpart;
    int ts = tpart;
    #pragma unroll
    for (int off = 32; off; off >>= 1) {
        es += __shfl_xor(es, off, 64);
        wsum += __shfl_xor(wsum, off, 64);
        ts += __shfl_xor(ts, off, 64);
    }

    if (ln == 0) {
        float degf = (float)dv;
        float k = degf + 1.0f;
        float E = 0.5f * (es + degf);
        float W = wsum + degf * (degf - 1.0f) * 0.5f;
        float T = (float)ts / 6.0f;
        float f3 = T;
        float f2 = W - 3.0f * T;
        float f1 = E * (k - 2.0f) - 2.0f * f2 - 3.0f * f3;
        float tot = k * (k - 1.0f) * (k - 2.0f) / 6.0f;
        float f0 = tot - f1 - f2 - f3;
        if (k < 3.0f) { f0 = f1 = f2 = f3 = 0.f; }
        float s = f0 + f1 + f2 + f3 + 1e-10f;
        feats[v * 16 + 0] = f0 / s;
        feats[v * 16 + 1] = f1 / s;
        feats[v * 16 + 2] = f2 / s;
        feats[v * 16 + 3] = f3 / s;
        feats[v * 16 + 12] = degf;
        feats[v * 16 + 13] = degf * degf;
        feats[v * 16 + 14] = degf;   // diag(A^2) = deg for symmetric 0/1
    }
}

// ---------------------------------------------------------------------------
// K3: a2 = adj @ adj built sparsely via LDS scatter, emitted as packed CSR:
// entry = (val << 16) | col. One block per row. Values are small ints (<64).
// Row order of entries is scrambled by the atomic slot-grab — harmless, all
// downstream uses are order-invariant.
// ---------------------------------------------------------------------------
__global__ __launch_bounds__(256) void a2_k(const int* __restrict__ nbr,
                                            const int* __restrict__ deg,
                                            unsigned int* __restrict__ csr,
                                            int* __restrict__ cnt) {
    __shared__ unsigned int acc[NN];
    __shared__ unsigned int base_s;
    int tid = threadIdx.x;
    int v = blockIdx.x;
    for (int j = tid; j < NN; j += 256) acc[j] = 0u;
    if (tid == 0) base_s = 0u;
    __syncthreads();
    int dv = min(deg[v], 64);
    for (int p = tid; p < dv * 64; p += 256) {
        int u = nbr[v * 64 + (p >> 6)];
        int wi = p & 63;
        if (wi < min(deg[u], 64)) atomicAdd(&acc[nbr[u * 64 + wi]], 1u);
    }
    __syncthreads();
    int j0 = tid * 16;
    unsigned int local = 0;
    #pragma unroll
    for (int m = 0; m < 16; m++) local += (acc[j0 + m] != 0u);
    unsigned int pos = atomicAdd(&base_s, local);
    unsigned int* dst = csr + (size_t)v * MAXNZ;
    #pragma unroll
    for (int m = 0; m < 16; m++) {
        unsigned int a = acc[j0 + m];
        if (a) {
            if (pos < MAXNZ) dst[pos] = (a << 16) | (unsigned int)(j0 + m);
            pos++;
        }
    }
    __syncthreads();
    if (tid == 0) cnt[v] = (int)min(base_s, (unsigned int)MAXNZ);
}

// ---------------------------------------------------------------------------
// K4: fused sparse a4-row + top-8.  a4[v,:] = sum_u a2[v,u] * a2[u,:] built
// in a uint LDS accumulator (exact integer arithmetic == fp32 reference),
// then block-level top-8 extraction -> feats cols 4..11.
// One block per row; rowv[i]/cnt[u] are wave-uniform -> scalar loads.
// ---------------------------------------------------------------------------
__global__ __launch_bounds__(256) void a4row_k(const unsigned int* __restrict__ csr,
                                               const int* __restrict__ cnt,
                                               float* __restrict__ feats) {
    __shared__ unsigned int acc[NN];
    __shared__ unsigned int wmax[4];
    __shared__ int winner;
    int tid = threadIdx.x;
    int wv = tid >> 6, ln = tid & 63;
    int v = blockIdx.x;

    for (int j = tid; j < NN; j += 256) acc[j] = 0u;
    __syncthreads();

    int nv = cnt[v];
    const unsigned int* rowv = csr + (size_t)v * MAXNZ;
    for (int i = 0; i < nv; i++) {
        unsigned int e = rowv[i];              // uniform -> s_load
        int u = (int)(e & 0xFFFFu);
        unsigned int w = e >> 16;
        int nu = cnt[u];                       // uniform -> s_load
        const unsigned int* rowu = csr + (size_t)u * MAXNZ;
        for (int j = tid; j < nu; j += 256) {
            unsigned int e2 = rowu[j];
            atomicAdd(&acc[e2 & 0xFFFFu], w * (e2 >> 16));
        }
    }
    __syncthreads();

    // per-thread top-8 over 16 coalesced LDS reads
    unsigned int best[8];
    #pragma unroll
    for (int i = 0; i < 8; i++) best[i] = 0u;
    #pragma unroll
    for (int m = 0; m < 16; m++) {
        unsigned int val = acc[tid + 256 * m];
        if (val > best[7]) {
            best[7] = val;
            #pragma unroll
            for (int s = 7; s > 0; s--) {
                if (best[s] > best[s - 1]) {
                    unsigned int t = best[s - 1]; best[s - 1] = best[s]; best[s] = t;
                } else break;
            }
        }
    }

    // 8 rounds of block max-extract
    for (int r = 0; r < 8; r++) {
        unsigned int m = best[0];
        #pragma unroll
        for (int off = 32; off; off >>= 1) m = max(m, (unsigned int)__shfl_xor((int)m, off, 64));
        if (ln == 0) wmax[wv] = m;
        if (tid == 0) winner = 256;
        __syncthreads();
        unsigned int M = max(max(wmax[0], wmax[1]), max(wmax[2], wmax[3]));
        if (best[0] == M) atomicMin(&winner, tid);
        __syncthreads();
        if (tid == winner) {
            #pragma unroll
            for (int s = 0; s < 7; s++) best[s] = best[s + 1];
            best[7] = 0u;
        }
        if (tid == 0) feats[v * 16 + 4 + r] = (float)M;
        __syncthreads();
    }
}

// ---------------------------------------------------------------------------
// K5: x = feats @ e_w + e_b   (4096x15 · 15x64)
// ---------------------------------------------------------------------------
__global__ __launch_bounds__(64) void embed_k(const float* __restrict__ feats,
                                              const float* __restrict__ e_w,
                                              const float* __restrict__ e_b,
                                              float* __restrict__ x) {
    int v = blockIdx.x, d = threadIdx.x;
    float s = e_b[d];
    #pragma unroll
    for (int j = 0; j < 15; j++) s += feats[v * 16 + j] * e_w[j * 64 + d];
    x[(size_t)v * 64 + d] = s;
}

// ---------------------------------------------------------------------------
// K6: one GNN layer: h = (1+eps)x + A x ; x' = relu(h W1 + b1) W2 + b2
// One wave per node; sparse aggregation over neighbor list.
// ---------------------------------------------------------------------------
__global__ __launch_bounds__(64) void layer_k(const float* __restrict__ xin,
                                              float* __restrict__ xout,
                                              const float* __restrict__ w1,
                                              const float* __restrict__ b1,
                                              const float* __restrict__ w2,
                                              const float* __restrict__ b2,
                                              const float* __restrict__ eps,
                                              const int* __restrict__ nbr,
                                              const int* __restrict__ deg,
                                              int li) {
    __shared__ float h[64], t[64];
    int v = blockIdx.x, d = threadIdx.x;
    float xv = xin[(size_t)v * 64 + d];
    float agg = 0.f;
    int dv = min(deg[v], 64);
    for (int j = 0; j < dv; j++) agg += xin[(size_t)nbr[v * 64 + j] * 64 + d];
    float hv = (1.0f + eps[li]) * xv + agg;
    h[d] = hv;
    __syncthreads();
    float s = b1[li * 64 + d];
    #pragma unroll 8
    for (int j = 0; j < 64; j++) s += h[j] * w1[li * 4096 + j * 64 + d];
    s = fmaxf(s, 0.f);
    t[d] = s;
    __syncthreads();
    float o = b2[li * 64 + d];
    #pragma unroll 8
    for (int j = 0; j < 64; j++) o += t[j] * w2[li * 4096 + j * 64 + d];
    xout[(size_t)v * 64 + d] = o;
}

// ---------------------------------------------------------------------------
// K7/K8: deterministic two-stage column sum: out = x.sum(0)
// ---------------------------------------------------------------------------
__global__ __launch_bounds__(256) void sum_k(const float* __restrict__ x,
                                             float* __restrict__ partial) {
    __shared__ float p[256];
    int tid = threadIdx.x;
    int d = tid & 63, g = tid >> 6;
    float s = 0.f;
    for (int v = blockIdx.x * 4 + g; v < NN; v += 1024)
        s += x[(size_t)v * 64 + d];
    p[tid] = s;
    __syncthreads();
    if (tid < 64)
        partial[blockIdx.x * 64 + tid] = p[tid] + p[tid + 64] + p[tid + 128] + p[tid + 192];
}

__global__ __launch_bounds__(256) void final_k(const float* __restrict__ partial,
                                               float* __restrict__ out) {
    __shared__ float p[256];
    int tid = threadIdx.x;
    int d = tid & 63, g = tid >> 6;
    float s = 0.f;
    for (int b = g; b < 256; b += 4) s += partial[b * 64 + d];
    p[tid] = s;
    __syncthreads();
    if (tid < 64) out[tid] = p[tid] + p[tid + 64] + p[tid + 128] + p[tid + 192];
}

// ---------------------------------------------------------------------------
extern "C" void kernel_launch(void* const* d_in, const int* in_sizes, int n_in,
                              void* d_out, int out_size, void* d_ws, size_t ws_size,
                              hipStream_t stream) {
    const float* adj = (const float*)d_in[0];
    const float* e_w = (const float*)d_in[1];
    const float* e_b = (const float*)d_in[2];
    const float* w1  = (const float*)d_in[3];
    const float* b1  = (const float*)d_in[4];
    const float* w2  = (const float*)d_in[5];
    const float* b2  = (const float*)d_in[6];
    const float* eps = (const float*)d_in[7];
    float* out = (float*)d_out;

    char* ws = (char*)d_ws;
    // workspace carve-up (~28.7 MB total)
    unsigned int* csr     = (unsigned int*)(ws);                  // 4096*1536*4 = 24 MB
    int*          nbr     = (int*)(ws + 25165824);                // 1 MB
    int*          deg     = (int*)(ws + 26214400);                // 16 KB
    int*          cnt     = (int*)(ws + 26230784);                // 16 KB
    float*        feats   = (float*)(ws + 26247168);              // 256 KB (4096x16, col 15 pad)
    float*        x0      = (float*)(ws + 26509312);              // 1 MB
    float*        x1      = (float*)(ws + 27557888);              // 1 MB
    float*        partial = (float*)(ws + 28606464);              // 64 KB

    nbr_k<<<1024, 256, 0, stream>>>(adj, nbr, deg);
    crfeat_k<<<1024, 256, 0, stream>>>(adj, nbr, deg, feats);
    a2_k<<<4096, 256, 0, stream>>>(nbr, deg, csr, cnt);
    a4row_k<<<4096, 256, 0, stream>>>(csr, cnt, feats);
    embed_k<<<4096, 64, 0, stream>>>(feats, e_w, e_b, x0);
    layer_k<<<4096, 64, 0, stream>>>(x0, x1, w1, b1, w2, b2, eps, nbr, deg, 0);
    layer_k<<<4096, 64, 0, stream>>>(x1, x0, w1, b1, w2, b2, eps, nbr, deg, 1);
    layer_k<<<4096, 64, 0, stream>>>(x0, x1, w1, b1, w2, b2, eps, nbr, deg, 2);
    sum_k<<<256, 256, 0, stream>>>(x1, partial);
    final_k<<<1, 256, 0, stream>>>(partial, out);
}

// Round 3
// 400.219 us; speedup vs baseline: 1.4144x; 1.4144x over previous
//
#include <hip/hip_runtime.h>
#include <hip/hip_bf16.h>
#include <stdint.h>

#define NN 4096
#define MAXNZ 1536   // cap on nnz per row of a2 (expected ~270)

// ---------------------------------------------------------------------------
// K1: build sorted neighbor lists (ascending col index) + true degree.
// One wave per row; ballot-compaction preserves index order.
// ---------------------------------------------------------------------------
__global__ __launch_bounds__(256) void nbr_k(const float* __restrict__ adj,
                                             int* __restrict__ nbr,
                                             int* __restrict__ deg) {
    int tid = threadIdx.x;
    int wv = tid >> 6, ln = tid & 63;
    int v = blockIdx.x * 4 + wv;
    size_t rb = (size_t)v * NN;
    int total = 0;
    for (int base = 0; base < NN; base += 64) {
        float val = adj[rb + base + ln];
        bool p = val > 0.5f;
        unsigned long long m = __ballot(p);
        if (p) {
            int pos = total + __popcll(m & ((1ull << ln) - 1ull));
            if (pos < 64) nbr[v * 64 + pos] = base + ln;
        }
        total += __popcll(m);
    }
    if (ln == 0) deg[v] = total;
}

// ---------------------------------------------------------------------------
// K2: cr_feat (cols 0..3) + degree_feat (cols 12..14). One wave per node.
// ---------------------------------------------------------------------------
__global__ __launch_bounds__(256) void crfeat_k(const float* __restrict__ adj,
                                                const int* __restrict__ nbr,
                                                const int* __restrict__ deg,
                                                float* __restrict__ feats) {
    __shared__ unsigned long long rows[4][64];
    __shared__ int mems[4][64];
    int tid = threadIdx.x;
    int wv = tid >> 6, ln = tid & 63;
    int v = blockIdx.x * 4 + wv;

    int dv = deg[v];
    int degL = min(dv, 64);
    int c = min(dv + 1, 64);

    int isless = (ln < degL && nbr[v * 64 + ln] < v) ? 1 : 0;
    int pos = isless;
    #pragma unroll
    for (int off = 32; off; off >>= 1) pos += __shfl_xor(pos, off, 64);

    int mem = 0;
    if (ln < c) {
        if (ln < pos)       mem = nbr[v * 64 + ln];
        else if (ln == pos) mem = v;
        else                mem = nbr[v * 64 + ln - 1];
    }
    mems[wv][ln] = mem;
    __syncthreads();

    unsigned long long mask = 0;
    if (ln < c) {
        if (ln == pos) {
            mask = (c >= 64 ? ~0ull : ((1ull << c) - 1ull)) ^ (1ull << pos);
        } else {
            size_t rowbase = (size_t)mem * NN;
            for (int j = 0; j < c; j++) {
                if (j == ln) continue;
                int mj = mems[wv][j];
                if (adj[rowbase + mj] > 0.5f) mask |= 1ull << j;
            }
        }
    }
    rows[wv][ln] = mask;
    __syncthreads();

    int tpart = 0;
    float epart = 0.f, wpart = 0.f;
    if (ln < c) {
        unsigned long long mm = mask;
        while (mm) {
            int j = __ffsll(mm) - 1;
            mm &= mm - 1;
            tpart += __popcll(mask & rows[wv][j]);
        }
        if (ln != pos) {
            int cn = __popcll(rows[wv][pos] & mask);
            float D = (float)cn + 1.0f;
            epart = D;
            wpart = D * (D - 1.0f) * 0.5f;
        }
    }
    float es = epart, wsum = wpart;
    int ts = tpart;
    #pragma unroll
    for (int off = 32; off; off >>= 1) {
        es += __shfl_xor(es, off, 64);
        wsum += __shfl_xor(wsum, off, 64);
        ts += __shfl_xor(ts, off, 64);
    }

    if (ln == 0) {
        float degf = (float)dv;
        float k = degf + 1.0f;
        float E = 0.5f * (es + degf);
        float W = wsum + degf * (degf - 1.0f) * 0.5f;
        float T = (float)ts / 6.0f;
        float f3 = T;
        float f2 = W - 3.0f * T;
        float f1 = E * (k - 2.0f) - 2.0f * f2 - 3.0f * f3;
        float tot = k * (k - 1.0f) * (k - 2.0f) / 6.0f;
        float f0 = tot - f1 - f2 - f3;
        if (k < 3.0f) { f0 = f1 = f2 = f3 = 0.f; }
        float s = f0 + f1 + f2 + f3 + 1e-10f;
        feats[v * 16 + 0] = f0 / s;
        feats[v * 16 + 1] = f1 / s;
        feats[v * 16 + 2] = f2 / s;
        feats[v * 16 + 3] = f3 / s;
        feats[v * 16 + 12] = degf;
        feats[v * 16 + 13] = degf * degf;
        feats[v * 16 + 14] = degf;   // diag(A^2) = deg for symmetric 0/1
    }
}

// ---------------------------------------------------------------------------
// K3: a2 = adj @ adj built sparsely via LDS scatter, emitted as packed CSR:
// entry = (val << 16) | col. One block per row.
// ---------------------------------------------------------------------------
__global__ __launch_bounds__(256) void a2_k(const int* __restrict__ nbr,
                                            const int* __restrict__ deg,
                                            unsigned int* __restrict__ csr,
                                            int* __restrict__ cnt) {
    __shared__ unsigned int acc[NN];
    __shared__ unsigned int base_s;
    int tid = threadIdx.x;
    int v = blockIdx.x;
    for (int j = tid; j < NN; j += 256) acc[j] = 0u;
    if (tid == 0) base_s = 0u;
    __syncthreads();
    int dv = min(deg[v], 64);
    for (int p = tid; p < dv * 64; p += 256) {
        int u = nbr[v * 64 + (p >> 6)];
        int wi = p & 63;
        if (wi < min(deg[u], 64)) atomicAdd(&acc[nbr[u * 64 + wi]], 1u);
    }
    __syncthreads();
    int j0 = tid * 16;
    unsigned int local = 0;
    #pragma unroll
    for (int m = 0; m < 16; m++) local += (acc[j0 + m] != 0u);
    unsigned int pos = atomicAdd(&base_s, local);
    unsigned int* dst = csr + (size_t)v * MAXNZ;
    #pragma unroll
    for (int m = 0; m < 16; m++) {
        unsigned int a = acc[j0 + m];
        if (a) {
            if (pos < MAXNZ) dst[pos] = (a << 16) | (unsigned int)(j0 + m);
            pos++;
        }
    }
    __syncthreads();
    if (tid == 0) cnt[v] = (int)min(base_s, (unsigned int)MAXNZ);
}

// ---------------------------------------------------------------------------
// K4: fused sparse a4-row + top-8, RESTRUCTURED:
//  - stage row-v entries AND cnt[u] for every u into LDS up front (coalesced)
//  - outer loop distributed across the 4 waves (i = wv; i += 4)
//  - inner row consumed with uint4 loads: 4 entries/lane, 256/round
// One block per row v; exact integer arithmetic in a uint LDS accumulator.
// ---------------------------------------------------------------------------
__global__ __launch_bounds__(256) void a4row_k(const unsigned int* __restrict__ csr,
                                               const int* __restrict__ cnt,
                                               float* __restrict__ feats) {
    __shared__ unsigned int acc[NN];          // 16 KB
    __shared__ unsigned int rowe[MAXNZ];      // 6 KB
    __shared__ unsigned short cnts[MAXNZ];    // 3 KB
    __shared__ unsigned int wmax[4];
    __shared__ int winner;
    int tid = threadIdx.x;
    int wv = tid >> 6, ln = tid & 63;
    int v = blockIdx.x;

    for (int j = tid; j < NN; j += 256) acc[j] = 0u;

    int nv = cnt[v];
    const unsigned int* rowv = csr + (size_t)v * MAXNZ;
    for (int i = tid; i < nv; i += 256) {
        unsigned int e = rowv[i];
        rowe[i] = e;
        cnts[i] = (unsigned short)cnt[e & 0xFFFFu];
    }
    __syncthreads();

    for (int i = wv; i < nv; i += 4) {
        unsigned int e = rowe[i];
        int u = (int)(e & 0xFFFFu);
        unsigned int w = e >> 16;
        int nu = cnts[i];
        const uint4* rowu = (const uint4*)(csr + (size_t)u * MAXNZ);
        for (int j = ln; j * 4 < nu; j += 64) {
            uint4 e4 = rowu[j];
            int base = j * 4;
            if (base + 0 < nu) atomicAdd(&acc[e4.x & 0xFFFFu], w * (e4.x >> 16));
            if (base + 1 < nu) atomicAdd(&acc[e4.y & 0xFFFFu], w * (e4.y >> 16));
            if (base + 2 < nu) atomicAdd(&acc[e4.z & 0xFFFFu], w * (e4.z >> 16));
            if (base + 3 < nu) atomicAdd(&acc[e4.w & 0xFFFFu], w * (e4.w >> 16));
        }
    }
    __syncthreads();

    // per-thread top-8 over 16 coalesced LDS reads
    unsigned int best[8];
    #pragma unroll
    for (int i = 0; i < 8; i++) best[i] = 0u;
    #pragma unroll
    for (int m = 0; m < 16; m++) {
        unsigned int val = acc[tid + 256 * m];
        if (val > best[7]) {
            best[7] = val;
            #pragma unroll
            for (int s = 7; s > 0; s--) {
                if (best[s] > best[s - 1]) {
                    unsigned int t = best[s - 1]; best[s - 1] = best[s]; best[s] = t;
                } else break;
            }
        }
    }

    // 8 rounds of block max-extract
    for (int r = 0; r < 8; r++) {
        unsigned int m = best[0];
        #pragma unroll
        for (int off = 32; off; off >>= 1) m = max(m, (unsigned int)__shfl_xor((int)m, off, 64));
        if (ln == 0) wmax[wv] = m;
        if (tid == 0) winner = 256;
        __syncthreads();
        unsigned int M = max(max(wmax[0], wmax[1]), max(wmax[2], wmax[3]));
        if (best[0] == M) atomicMin(&winner, tid);
        __syncthreads();
        if (tid == winner) {
            #pragma unroll
            for (int s = 0; s < 7; s++) best[s] = best[s + 1];
            best[7] = 0u;
        }
        if (tid == 0) feats[v * 16 + 4 + r] = (float)M;
        __syncthreads();
    }
}

// ---------------------------------------------------------------------------
// K5: x = feats @ e_w + e_b   (4 nodes per 256-thread block)
// ---------------------------------------------------------------------------
__global__ __launch_bounds__(256) void embed_k(const float* __restrict__ feats,
                                               const float* __restrict__ e_w,
                                               const float* __restrict__ e_b,
                                               float* __restrict__ x) {
    int tid = threadIdx.x;
    int wv = tid >> 6, d = tid & 63;
    int v = blockIdx.x * 4 + wv;
    float s = e_b[d];
    #pragma unroll
    for (int j = 0; j < 15; j++) s += feats[v * 16 + j] * e_w[j * 64 + d];
    x[(size_t)v * 64 + d] = s;
}

// ---------------------------------------------------------------------------
// K6: one GNN layer: h = (1+eps)x + A x ; x' = relu(h W1 + b1) W2 + b2
// 4 nodes per 256-thread block (one wave each); neighbor gather unrolled x4
// to keep 4 loads in flight.
// ---------------------------------------------------------------------------
__global__ __launch_bounds__(256) void layer_k(const float* __restrict__ xin,
                                               float* __restrict__ xout,
                                               const float* __restrict__ w1,
                                               const float* __restrict__ b1,
                                               const float* __restrict__ w2,
                                               const float* __restrict__ b2,
                                               const float* __restrict__ eps,
                                               const int* __restrict__ nbr,
                                               const int* __restrict__ deg,
                                               int li) {
    __shared__ float h[4][64], t[4][64];
    int tid = threadIdx.x;
    int wv = tid >> 6, d = tid & 63;
    int v = blockIdx.x * 4 + wv;
    float xv = xin[(size_t)v * 64 + d];
    int dv = min(deg[v], 64);
    const int* nl = nbr + v * 64;
    float agg = 0.f;
    int j = 0;
    for (; j + 4 <= dv; j += 4) {
        int n0 = nl[j], n1 = nl[j + 1], n2 = nl[j + 2], n3 = nl[j + 3];
        float a0 = xin[(size_t)n0 * 64 + d];
        float a1 = xin[(size_t)n1 * 64 + d];
        float a2v = xin[(size_t)n2 * 64 + d];
        float a3 = xin[(size_t)n3 * 64 + d];
        agg += (a0 + a1) + (a2v + a3);
    }
    for (; j < dv; j++) agg += xin[(size_t)nl[j] * 64 + d];
    float hv = (1.0f + eps[li]) * xv + agg;
    h[wv][d] = hv;
    __syncthreads();
    float s = b1[li * 64 + d];
    #pragma unroll 8
    for (int k = 0; k < 64; k++) s += h[wv][k] * w1[li * 4096 + k * 64 + d];
    s = fmaxf(s, 0.f);
    t[wv][d] = s;
    __syncthreads();
    float o = b2[li * 64 + d];
    #pragma unroll 8
    for (int k = 0; k < 64; k++) o += t[wv][k] * w2[li * 4096 + k * 64 + d];
    xout[(size_t)v * 64 + d] = o;
}

// ---------------------------------------------------------------------------
// K7/K8: deterministic two-stage column sum: out = x.sum(0)
// ---------------------------------------------------------------------------
__global__ __launch_bounds__(256) void sum_k(const float* __restrict__ x,
                                             float* __restrict__ partial) {
    __shared__ float p[256];
    int tid = threadIdx.x;
    int d = tid & 63, g = tid >> 6;
    float s = 0.f;
    for (int v = blockIdx.x * 4 + g; v < NN; v += 1024)
        s += x[(size_t)v * 64 + d];
    p[tid] = s;
    __syncthreads();
    if (tid < 64)
        partial[blockIdx.x * 64 + tid] = p[tid] + p[tid + 64] + p[tid + 128] + p[tid + 192];
}

__global__ __launch_bounds__(256) void final_k(const float* __restrict__ partial,
                                               float* __restrict__ out) {
    __shared__ float p[256];
    int tid = threadIdx.x;
    int d = tid & 63, g = tid >> 6;
    float s = 0.f;
    for (int b = g; b < 256; b += 4) s += partial[b * 64 + d];
    p[tid] = s;
    __syncthreads();
    if (tid < 64) out[tid] = p[tid] + p[tid + 64] + p[tid + 128] + p[tid + 192];
}

// ---------------------------------------------------------------------------
extern "C" void kernel_launch(void* const* d_in, const int* in_sizes, int n_in,
                              void* d_out, int out_size, void* d_ws, size_t ws_size,
                              hipStream_t stream) {
    const float* adj = (const float*)d_in[0];
    const float* e_w = (const float*)d_in[1];
    const float* e_b = (const float*)d_in[2];
    const float* w1  = (const float*)d_in[3];
    const float* b1  = (const float*)d_in[4];
    const float* w2  = (const float*)d_in[5];
    const float* b2  = (const float*)d_in[6];
    const float* eps = (const float*)d_in[7];
    float* out = (float*)d_out;

    char* ws = (char*)d_ws;
    unsigned int* csr     = (unsigned int*)(ws);                  // 24 MB
    int*          nbr     = (int*)(ws + 25165824);                // 1 MB
    int*          deg     = (int*)(ws + 26214400);                // 16 KB
    int*          cnt     = (int*)(ws + 26230784);                // 16 KB
    float*        feats   = (float*)(ws + 26247168);              // 256 KB
    float*        x0      = (float*)(ws + 26509312);              // 1 MB
    float*        x1      = (float*)(ws + 27557888);              // 1 MB
    float*        partial = (float*)(ws + 28606464);              // 64 KB

    nbr_k<<<1024, 256, 0, stream>>>(adj, nbr, deg);
    crfeat_k<<<1024, 256, 0, stream>>>(adj, nbr, deg, feats);
    a2_k<<<4096, 256, 0, stream>>>(nbr, deg, csr, cnt);
    a4row_k<<<4096, 256, 0, stream>>>(csr, cnt, feats);
    embed_k<<<1024, 256, 0, stream>>>(feats, e_w, e_b, x0);
    layer_k<<<1024, 256, 0, stream>>>(x0, x1, w1, b1, w2, b2, eps, nbr, deg, 0);
    layer_k<<<1024, 256, 0, stream>>>(x1, x0, w1, b1, w2, b2, eps, nbr, deg, 1);
    layer_k<<<1024, 256, 0, stream>>>(x0, x1, w1, b1, w2, b2, eps, nbr, deg, 2);
    sum_k<<<256, 256, 0, stream>>>(x1, partial);
    final_k<<<1, 256, 0, stream>>>(partial, out);
}